// Round 3
// baseline (11906.089 us; speedup 1.0000x reference)
//
#include <hip/hip_runtime.h>
#include <hip/hip_bf16.h>
#include <math.h>

// PaiNN layer: N=50000 nodes, E=800000 edges, H=128, R=20 (derived at runtime).
// d_out layout: s_out [N,H] then v_out [N,3,H]. We use d_out itself as the
// aggregation buffer (agg_s / agg_v), zeroed by a grid-stride kernel, edge
// kernel atomically accumulates, node kernel finishes in place.

#define H 128
#define R 20
#define KX (H + R)          // 148
#define LN_EPS 1e-5f

#define BE 64               // edges per block (E divisible by 64)
#define XS_STRIDE 149       // odd stride -> conflict-free column reads
#define H1_STRIDE 129

#define BN 64               // nodes per block
#define US_STRIDE 257
#define H2_STRIDE 129

__device__ __forceinline__ float silu_f(float x) {
    return x / (1.0f + __expf(-x));
}

__global__ __launch_bounds__(256)
void zero_kernel(float4* __restrict__ p, long n4)
{
    const long stride = (long)gridDim.x * blockDim.x;
    for (long i = (long)blockIdx.x * blockDim.x + threadIdx.x; i < n4; i += stride)
        p[i] = make_float4(0.f, 0.f, 0.f, 0.f);
}

__global__ __launch_bounds__(256, 2)
void painn_edge_kernel(const float* __restrict__ s,
                       const float* __restrict__ v,
                       const float* __restrict__ rbf,
                       const float* __restrict__ evu,
                       const float* __restrict__ mW1,
                       const float* __restrict__ mb1,
                       const float* __restrict__ mW2,
                       const float* __restrict__ mb2,
                       const int*   __restrict__ eidx,
                       int E,
                       float* __restrict__ agg_s,   // [N,H]   (d_out part 0)
                       float* __restrict__ agg_v)   // [N,3,H] (d_out part 1)
{
    __shared__ float Xs[BE * XS_STRIDE];
    __shared__ float H1s[BE * H1_STRIDE];
    __shared__ float evus[BE][3];
    __shared__ int   srcs[BE];
    __shared__ int   dsts[BE];

    const int t  = threadIdx.x;
    const int e0 = blockIdx.x * BE;

    if (t < BE) {
        srcs[t] = eidx[e0 + t];          // edge_index row 0
        dsts[t] = eidx[E + e0 + t];      // edge_index row 1
    }
    if (t < BE * 3) {
        int r = t / 3, c = t - r * 3;
        evus[r][c] = evu[(e0 + r) * 3 + c];
    }
    __syncthreads();

    // ---- gather x = [s[src], rbf] into Xs ----
    #pragma unroll
    for (int it = 0; it < 8; ++it) {
        int idx = t + it * 256;          // 0..2047 -> 64 rows x 32 float4
        int row = idx >> 5;
        int c4  = (idx & 31) << 2;
        const float4 val = *reinterpret_cast<const float4*>(s + srcs[row] * H + c4);
        float* p = &Xs[row * XS_STRIDE + c4];
        p[0] = val.x; p[1] = val.y; p[2] = val.z; p[3] = val.w;
    }
    #pragma unroll
    for (int it = 0; it < 5; ++it) {
        int idx = t + it * 256;          // 0..1279 -> 64 rows x 20
        int row = idx / R;
        int c   = idx - row * R;
        Xs[row * XS_STRIDE + H + c] = rbf[(e0 + row) * R + c];
    }
    __syncthreads();

    const int ty = t >> 4;               // 0..15
    const int tx = t & 15;               // 0..15
    const int jb = tx << 3;              // output col base (8 cols/thread)
    const int er = ty << 2;              // edge row base (4 edges/thread)

    // ---- GEMM1: h1 = silu(x @ mW1 + mb1) ----
    {
        float acc[4][8];
        #pragma unroll
        for (int r2 = 0; r2 < 4; ++r2)
            #pragma unroll
            for (int j = 0; j < 8; ++j) acc[r2][j] = 0.f;

        const float* wp = mW1 + jb;
        for (int k = 0; k < KX; ++k) {
            const float4 w0 = *reinterpret_cast<const float4*>(wp);
            const float4 w1 = *reinterpret_cast<const float4*>(wp + 4);
            wp += H;
            float xk[4];
            #pragma unroll
            for (int r2 = 0; r2 < 4; ++r2) xk[r2] = Xs[(er + r2) * XS_STRIDE + k];
            #pragma unroll
            for (int r2 = 0; r2 < 4; ++r2) {
                acc[r2][0] += xk[r2] * w0.x;
                acc[r2][1] += xk[r2] * w0.y;
                acc[r2][2] += xk[r2] * w0.z;
                acc[r2][3] += xk[r2] * w0.w;
                acc[r2][4] += xk[r2] * w1.x;
                acc[r2][5] += xk[r2] * w1.y;
                acc[r2][6] += xk[r2] * w1.z;
                acc[r2][7] += xk[r2] * w1.w;
            }
        }
        const float4 b0 = *reinterpret_cast<const float4*>(mb1 + jb);
        const float4 b1 = *reinterpret_cast<const float4*>(mb1 + jb + 4);
        const float bias[8] = {b0.x, b0.y, b0.z, b0.w, b1.x, b1.y, b1.z, b1.w};
        #pragma unroll
        for (int r2 = 0; r2 < 4; ++r2) {
            #pragma unroll
            for (int j = 0; j < 8; ++j) {
                float a = acc[r2][j] + bias[j];
                H1s[(er + r2) * H1_STRIDE + jb + j] = silu_f(a);
            }
        }
    }
    __syncthreads();

    // ---- GEMM2 chunk 0: a_ss, scatter to agg_s ----
    {
        float acc[4][8];
        #pragma unroll
        for (int r2 = 0; r2 < 4; ++r2)
            #pragma unroll
            for (int j = 0; j < 8; ++j) acc[r2][j] = 0.f;

        const float* wp = mW2 + jb;
        for (int k = 0; k < H; ++k) {
            const float4 w0 = *reinterpret_cast<const float4*>(wp);
            const float4 w1 = *reinterpret_cast<const float4*>(wp + 4);
            wp += 3 * H;
            float hk[4];
            #pragma unroll
            for (int r2 = 0; r2 < 4; ++r2) hk[r2] = H1s[(er + r2) * H1_STRIDE + k];
            #pragma unroll
            for (int r2 = 0; r2 < 4; ++r2) {
                acc[r2][0] += hk[r2] * w0.x;
                acc[r2][1] += hk[r2] * w0.y;
                acc[r2][2] += hk[r2] * w0.z;
                acc[r2][3] += hk[r2] * w0.w;
                acc[r2][4] += hk[r2] * w1.x;
                acc[r2][5] += hk[r2] * w1.y;
                acc[r2][6] += hk[r2] * w1.z;
                acc[r2][7] += hk[r2] * w1.w;
            }
        }
        const float4 b0 = *reinterpret_cast<const float4*>(mb2 + jb);
        const float4 b1 = *reinterpret_cast<const float4*>(mb2 + jb + 4);
        const float bias[8] = {b0.x, b0.y, b0.z, b0.w, b1.x, b1.y, b1.z, b1.w};
        #pragma unroll
        for (int r2 = 0; r2 < 4; ++r2) {
            float* base = agg_s + dsts[er + r2] * H + jb;
            #pragma unroll
            for (int j = 0; j < 8; ++j)
                unsafeAtomicAdd(base + j, acc[r2][j] + bias[j]);
        }
    }

    // ---- GEMM2 chunks 1&2: a_sv, a_vv; combine with evu and v[src]; scatter ----
    {
        float asv[4][8], avv[4][8];
        #pragma unroll
        for (int r2 = 0; r2 < 4; ++r2)
            #pragma unroll
            for (int j = 0; j < 8; ++j) { asv[r2][j] = 0.f; avv[r2][j] = 0.f; }

        const float* wp = mW2 + H + jb;       // cols [128..256) and [256..384)
        for (int k = 0; k < H; ++k) {
            const float4 s0 = *reinterpret_cast<const float4*>(wp);
            const float4 s1 = *reinterpret_cast<const float4*>(wp + 4);
            const float4 v0 = *reinterpret_cast<const float4*>(wp + H);
            const float4 v1 = *reinterpret_cast<const float4*>(wp + H + 4);
            wp += 3 * H;
            float hk[4];
            #pragma unroll
            for (int r2 = 0; r2 < 4; ++r2) hk[r2] = H1s[(er + r2) * H1_STRIDE + k];
            #pragma unroll
            for (int r2 = 0; r2 < 4; ++r2) {
                asv[r2][0] += hk[r2] * s0.x;  avv[r2][0] += hk[r2] * v0.x;
                asv[r2][1] += hk[r2] * s0.y;  avv[r2][1] += hk[r2] * v0.y;
                asv[r2][2] += hk[r2] * s0.z;  avv[r2][2] += hk[r2] * v0.z;
                asv[r2][3] += hk[r2] * s0.w;  avv[r2][3] += hk[r2] * v0.w;
                asv[r2][4] += hk[r2] * s1.x;  avv[r2][4] += hk[r2] * v1.x;
                asv[r2][5] += hk[r2] * s1.y;  avv[r2][5] += hk[r2] * v1.y;
                asv[r2][6] += hk[r2] * s1.z;  avv[r2][6] += hk[r2] * v1.z;
                asv[r2][7] += hk[r2] * s1.w;  avv[r2][7] += hk[r2] * v1.w;
            }
        }
        const float4 bs0 = *reinterpret_cast<const float4*>(mb2 + H + jb);
        const float4 bs1 = *reinterpret_cast<const float4*>(mb2 + H + jb + 4);
        const float4 bv0 = *reinterpret_cast<const float4*>(mb2 + 2 * H + jb);
        const float4 bv1 = *reinterpret_cast<const float4*>(mb2 + 2 * H + jb + 4);
        const float bsv[8] = {bs0.x, bs0.y, bs0.z, bs0.w, bs1.x, bs1.y, bs1.z, bs1.w};
        const float bvv[8] = {bv0.x, bv0.y, bv0.z, bv0.w, bv1.x, bv1.y, bv1.z, bv1.w};

        #pragma unroll
        for (int r2 = 0; r2 < 4; ++r2) {
            const int e  = er + r2;
            const int sn = srcs[e];
            const int dn = dsts[e];
            float msv[8], mvv[8];
            #pragma unroll
            for (int j = 0; j < 8; ++j) {
                msv[j] = asv[r2][j] + bsv[j];
                mvv[j] = avv[r2][j] + bvv[j];
            }
            #pragma unroll
            for (int d = 0; d < 3; ++d) {
                const float ed = evus[e][d];
                const float* vp = v + (sn * 3 + d) * H + jb;
                const float4 vv0 = *reinterpret_cast<const float4*>(vp);
                const float4 vv1 = *reinterpret_cast<const float4*>(vp + 4);
                const float vl[8] = {vv0.x, vv0.y, vv0.z, vv0.w, vv1.x, vv1.y, vv1.z, vv1.w};
                float* ob = agg_v + (dn * 3 + d) * H + jb;
                #pragma unroll
                for (int j = 0; j < 8; ++j)
                    unsafeAtomicAdd(ob + j, msv[j] * ed + mvv[j] * vl[j]);
            }
        }
    }
}

__global__ __launch_bounds__(256, 1)
void painn_node_kernel(const float* __restrict__ s,
                       const float* __restrict__ v,
                       const float* __restrict__ uW1,
                       const float* __restrict__ ub1,
                       const float* __restrict__ uW2,
                       const float* __restrict__ ub2,
                       const float* __restrict__ ln_g,
                       const float* __restrict__ ln_b,
                       int N,
                       float* __restrict__ out_s,   // in: agg_s, out: s_out
                       float* __restrict__ out_v)   // in: agg_v, out: v_out
{
    __shared__ float Us[BN * US_STRIDE];   // [64][256+pad] : [s+agg_s | v_norm], later y
    __shared__ float H2s[BN * H2_STRIDE];

    const int t  = threadIdx.x;
    const int n0 = blockIdx.x * BN;
    const int m  = min(BN, N - n0);

    // ---- load s+agg_s and compute v_norm into Us ----
    #pragma unroll
    for (int it = 0; it < 8; ++it) {
        int idx = t + it * 256;
        int row = idx >> 5;
        int c4  = (idx & 31) << 2;
        if (row < m) {
            const int nb = (n0 + row) * H + c4;
            const float4 sv = *reinterpret_cast<const float4*>(s + nb);
            const float4 av = *reinterpret_cast<const float4*>(out_s + nb);
            float* p = &Us[row * US_STRIDE + c4];
            p[0] = sv.x + av.x; p[1] = sv.y + av.y;
            p[2] = sv.z + av.z; p[3] = sv.w + av.w;

            float nx = 0.f, ny = 0.f, nz = 0.f, nw = 0.f;
            #pragma unroll
            for (int d = 0; d < 3; ++d) {
                const int vb = ((n0 + row) * 3 + d) * H + c4;
                const float4 vv = *reinterpret_cast<const float4*>(v + vb);
                const float4 avv = *reinterpret_cast<const float4*>(out_v + vb);
                const float a0 = vv.x + avv.x, a1 = vv.y + avv.y;
                const float a2 = vv.z + avv.z, a3 = vv.w + avv.w;
                nx += a0 * a0; ny += a1 * a1; nz += a2 * a2; nw += a3 * a3;
            }
            float* q = &Us[row * US_STRIDE + H + c4];
            q[0] = sqrtf(nx); q[1] = sqrtf(ny); q[2] = sqrtf(nz); q[3] = sqrtf(nw);
        }
    }
    __syncthreads();

    const int ty = t >> 4;
    const int tx = t & 15;
    const int jb = tx << 3;
    const int nr = ty << 2;

    // ---- GEMV1: silu(upd_in @ uW1 + ub1) -> H2s ----
    {
        float acc[4][8];
        #pragma unroll
        for (int r2 = 0; r2 < 4; ++r2)
            #pragma unroll
            for (int j = 0; j < 8; ++j) acc[r2][j] = 0.f;

        const float* wp = uW1 + jb;
        for (int k = 0; k < 2 * H; ++k) {
            const float4 w0 = *reinterpret_cast<const float4*>(wp);
            const float4 w1 = *reinterpret_cast<const float4*>(wp + 4);
            wp += H;
            float uk[4];
            #pragma unroll
            for (int r2 = 0; r2 < 4; ++r2) uk[r2] = Us[(nr + r2) * US_STRIDE + k];
            #pragma unroll
            for (int r2 = 0; r2 < 4; ++r2) {
                acc[r2][0] += uk[r2] * w0.x;
                acc[r2][1] += uk[r2] * w0.y;
                acc[r2][2] += uk[r2] * w0.z;
                acc[r2][3] += uk[r2] * w0.w;
                acc[r2][4] += uk[r2] * w1.x;
                acc[r2][5] += uk[r2] * w1.y;
                acc[r2][6] += uk[r2] * w1.z;
                acc[r2][7] += uk[r2] * w1.w;
            }
        }
        const float4 b0 = *reinterpret_cast<const float4*>(ub1 + jb);
        const float4 b1 = *reinterpret_cast<const float4*>(ub1 + jb + 4);
        const float bias[8] = {b0.x, b0.y, b0.z, b0.w, b1.x, b1.y, b1.z, b1.w};
        #pragma unroll
        for (int r2 = 0; r2 < 4; ++r2)
            #pragma unroll
            for (int j = 0; j < 8; ++j)
                H2s[(nr + r2) * H2_STRIDE + jb + j] = silu_f(acc[r2][j] + bias[j]);
    }
    __syncthreads();

    // ---- GEMV2: delta_s & gate; y = s + delta_s into Us ----
    float gate[4][8];
    {
        float ad[4][8], ag[4][8];
        #pragma unroll
        for (int r2 = 0; r2 < 4; ++r2)
            #pragma unroll
            for (int j = 0; j < 8; ++j) { ad[r2][j] = 0.f; ag[r2][j] = 0.f; }

        const float* wp = uW2 + jb;
        for (int k = 0; k < H; ++k) {
            const float4 d0 = *reinterpret_cast<const float4*>(wp);
            const float4 d1 = *reinterpret_cast<const float4*>(wp + 4);
            const float4 g0 = *reinterpret_cast<const float4*>(wp + H);
            const float4 g1 = *reinterpret_cast<const float4*>(wp + H + 4);
            wp += 2 * H;
            float hk[4];
            #pragma unroll
            for (int r2 = 0; r2 < 4; ++r2) hk[r2] = H2s[(nr + r2) * H2_STRIDE + k];
            #pragma unroll
            for (int r2 = 0; r2 < 4; ++r2) {
                ad[r2][0] += hk[r2] * d0.x;  ag[r2][0] += hk[r2] * g0.x;
                ad[r2][1] += hk[r2] * d0.y;  ag[r2][1] += hk[r2] * g0.y;
                ad[r2][2] += hk[r2] * d0.z;  ag[r2][2] += hk[r2] * g0.z;
                ad[r2][3] += hk[r2] * d0.w;  ag[r2][3] += hk[r2] * g0.w;
                ad[r2][4] += hk[r2] * d1.x;  ag[r2][4] += hk[r2] * g1.x;
                ad[r2][5] += hk[r2] * d1.y;  ag[r2][5] += hk[r2] * g1.y;
                ad[r2][6] += hk[r2] * d1.z;  ag[r2][6] += hk[r2] * g1.z;
                ad[r2][7] += hk[r2] * d1.w;  ag[r2][7] += hk[r2] * g1.w;
            }
        }
        const float4 bd0 = *reinterpret_cast<const float4*>(ub2 + jb);
        const float4 bd1 = *reinterpret_cast<const float4*>(ub2 + jb + 4);
        const float4 bg0 = *reinterpret_cast<const float4*>(ub2 + H + jb);
        const float4 bg1 = *reinterpret_cast<const float4*>(ub2 + H + jb + 4);
        const float bd[8] = {bd0.x, bd0.y, bd0.z, bd0.w, bd1.x, bd1.y, bd1.z, bd1.w};
        const float bg[8] = {bg0.x, bg0.y, bg0.z, bg0.w, bg1.x, bg1.y, bg1.z, bg1.w};

        #pragma unroll
        for (int r2 = 0; r2 < 4; ++r2) {
            #pragma unroll
            for (int j = 0; j < 8; ++j) gate[r2][j] = ag[r2][j] + bg[j];
            if (nr + r2 < m) {
                const int nb = (n0 + nr + r2) * H + jb;
                const float4 s0 = *reinterpret_cast<const float4*>(s + nb);
                const float4 s1 = *reinterpret_cast<const float4*>(s + nb + 4);
                const float sl[8] = {s0.x, s0.y, s0.z, s0.w, s1.x, s1.y, s1.z, s1.w};
                float* yp = &Us[(nr + r2) * US_STRIDE + jb];
                #pragma unroll
                for (int j = 0; j < 8; ++j) yp[j] = sl[j] + ad[r2][j] + bd[j];
            }
        }
    }
    __syncthreads();

    // ---- LayerNorm on y (4 threads per row) -> s_out ----
    {
        const int row = t >> 2;
        const int q   = t & 3;
        if (row < m) {
            float sum = 0.f, ss = 0.f;
            #pragma unroll
            for (int i = 0; i < 32; ++i) {
                const float val = Us[row * US_STRIDE + q * 32 + i];
                sum += val; ss += val * val;
            }
            sum += __shfl_xor(sum, 1); ss += __shfl_xor(ss, 1);
            sum += __shfl_xor(sum, 2); ss += __shfl_xor(ss, 2);
            const float mu   = sum * (1.0f / H);
            const float var  = ss * (1.0f / H) - mu * mu;
            const float rstd = rsqrtf(fmaxf(var, 0.f) + LN_EPS);
            #pragma unroll
            for (int i4 = 0; i4 < 8; ++i4) {
                const int c = q * 32 + i4 * 4;
                const float4 g = *reinterpret_cast<const float4*>(ln_g + c);
                const float4 b = *reinterpret_cast<const float4*>(ln_b + c);
                const float* yp = &Us[row * US_STRIDE + c];
                float4 o;
                o.x = (yp[0] - mu) * rstd * g.x + b.x;
                o.y = (yp[1] - mu) * rstd * g.y + b.y;
                o.z = (yp[2] - mu) * rstd * g.z + b.z;
                o.w = (yp[3] - mu) * rstd * g.w + b.w;
                *reinterpret_cast<float4*>(out_s + (n0 + row) * H + c) = o;
            }
        }
    }

    // ---- v_out = gate * (v + agg_v), in place over agg_v ----
    #pragma unroll
    for (int r2 = 0; r2 < 4; ++r2) {
        if (nr + r2 < m) {
            const int nn = n0 + nr + r2;
            #pragma unroll
            for (int d = 0; d < 3; ++d) {
                const int vb = (nn * 3 + d) * H + jb;
                const float4 vv0 = *reinterpret_cast<const float4*>(v + vb);
                const float4 vv1 = *reinterpret_cast<const float4*>(v + vb + 4);
                const float4 av0 = *reinterpret_cast<const float4*>(out_v + vb);
                const float4 av1 = *reinterpret_cast<const float4*>(out_v + vb + 4);
                float4 o0, o1;
                o0.x = gate[r2][0] * (vv0.x + av0.x);
                o0.y = gate[r2][1] * (vv0.y + av0.y);
                o0.z = gate[r2][2] * (vv0.z + av0.z);
                o0.w = gate[r2][3] * (vv0.w + av0.w);
                o1.x = gate[r2][4] * (vv1.x + av1.x);
                o1.y = gate[r2][5] * (vv1.y + av1.y);
                o1.z = gate[r2][6] * (vv1.z + av1.z);
                o1.w = gate[r2][7] * (vv1.w + av1.w);
                *reinterpret_cast<float4*>(out_v + vb)     = o0;
                *reinterpret_cast<float4*>(out_v + vb + 4) = o1;
            }
        }
    }
}

extern "C" void kernel_launch(void* const* d_in, const int* in_sizes, int n_in,
                              void* d_out, int out_size, void* d_ws, size_t ws_size,
                              hipStream_t stream)
{
    const float* s    = (const float*)d_in[0];
    const float* v    = (const float*)d_in[1];
    const float* rbf  = (const float*)d_in[2];
    const float* evu  = (const float*)d_in[3];
    const float* mW1  = (const float*)d_in[4];
    const float* mb1  = (const float*)d_in[5];
    const float* mW2  = (const float*)d_in[6];
    const float* mb2  = (const float*)d_in[7];
    const float* uW1  = (const float*)d_in[8];
    const float* ub1  = (const float*)d_in[9];
    const float* uW2  = (const float*)d_in[10];
    const float* ub2  = (const float*)d_in[11];
    const float* ln_g = (const float*)d_in[12];
    const float* ln_b = (const float*)d_in[13];
    const int*   eidx = (const int*)d_in[14];

    const int N = in_sizes[0] / H;   // 50000
    const int E = in_sizes[2] / R;   // 800000

    float* agg_s = (float*)d_out;                 // [N,H]
    float* agg_v = (float*)d_out + (size_t)N * H; // [N,3,H]

    // zero the aggregation buffers (d_out is re-poisoned to 0xAA before every call)
    const long n4 = (long)N * 4 * H / 4;          // float4 count
    zero_kernel<<<dim3(2048), dim3(256), 0, stream>>>((float4*)d_out, n4);

    painn_edge_kernel<<<dim3(E / BE), dim3(256), 0, stream>>>(
        s, v, rbf, evu, mW1, mb1, mW2, mb2, eidx, E, agg_s, agg_v);

    painn_node_kernel<<<dim3((N + BN - 1) / BN), dim3(256), 0, stream>>>(
        s, v, uW1, ub1, uW2, ub2, ln_g, ln_b, N, agg_s, agg_v);
}

// Round 4
// 2518.975 us; speedup vs baseline: 4.7266x; 4.7266x over previous
//
#include <hip/hip_runtime.h>
#include <hip/hip_bf16.h>
#include <math.h>

// PaiNN layer: N=50000 nodes, E=800000 edges, H=128, R=20.
// Round 4 design: destination-sorted edge processing.
//   1. counting sort of edges by dst (hist -> scan -> scatter) in d_ws
//   2. edge kernel walks sorted edges; per-edge outputs staged in LDS and
//      collapsed by segmented run-sum (consecutive equal dst) so atomics
//      shrink ~10x and land on lines owned by ~1 block (no XCD ping-pong).
//   3. node kernel finishes in place over d_out.
// d_out layout: s_out [N,H] then v_out [N,3,H]; used as agg buffers first.

#define H 128
#define R 20
#define KX (H + R)          // 148
#define LN_EPS 1e-5f

#define BE 64               // edges per block (E divisible by 64)
#define XS_STRIDE 149       // odd stride -> conflict-free column reads
#define H1_STRIDE 129

#define BN 64               // nodes per block
#define US_STRIDE 257
#define H2_STRIDE 129

__device__ __forceinline__ float silu_f(float x) {
    return x / (1.0f + __expf(-x));
}

__global__ __launch_bounds__(256)
void zero_f4_kernel(float4* __restrict__ p, long n4)
{
    const long stride = (long)gridDim.x * blockDim.x;
    for (long i = (long)blockIdx.x * blockDim.x + threadIdx.x; i < n4; i += stride)
        p[i] = make_float4(0.f, 0.f, 0.f, 0.f);
}

__global__ __launch_bounds__(256)
void zero_i_kernel(int* __restrict__ p, int n)
{
    const int stride = gridDim.x * blockDim.x;
    for (int i = blockIdx.x * blockDim.x + threadIdx.x; i < n; i += stride)
        p[i] = 0;
}

// histogram of destination nodes
__global__ __launch_bounds__(256)
void hist_kernel(const int* __restrict__ eidx, int E, int* __restrict__ cnt)
{
    const int stride = gridDim.x * blockDim.x;
    for (int i = blockIdx.x * blockDim.x + threadIdx.x; i < E; i += stride)
        atomicAdd(&cnt[eidx[E + i]], 1);
}

// single-block exclusive scan: fill[i] = sum(cnt[0..i))
__global__ __launch_bounds__(1024, 1)
void scan_kernel(const int* __restrict__ cnt, int N, int* __restrict__ fill)
{
    __shared__ int lds[1024];
    __shared__ int base_s;
    const int tid = threadIdx.x;
    if (tid == 0) base_s = 0;
    __syncthreads();
    const int nchunk = (N + 1023) >> 10;
    for (int c = 0; c < nchunk; ++c) {
        const int i   = (c << 10) + tid;
        const int val = (i < N) ? cnt[i] : 0;
        lds[tid] = val;
        __syncthreads();
        for (int off = 1; off < 1024; off <<= 1) {      // Hillis-Steele inclusive
            int t = (tid >= off) ? lds[tid - off] : 0;
            __syncthreads();
            lds[tid] += t;
            __syncthreads();
        }
        const int incl = lds[tid];
        if (i < N) fill[i] = base_s + (incl - val);     // exclusive
        __syncthreads();
        if (tid == 1023) base_s += incl;                // chunk total
        __syncthreads();
    }
}

// scatter edge ids into destination-sorted order
__global__ __launch_bounds__(256)
void scatter_kernel(const int* __restrict__ eidx, int E,
                    int* __restrict__ fill, int* __restrict__ sorted)
{
    const int stride = gridDim.x * blockDim.x;
    for (int i = blockIdx.x * blockDim.x + threadIdx.x; i < E; i += stride) {
        const int d    = eidx[E + i];
        const int slot = atomicAdd(&fill[d], 1);
        sorted[slot] = i;
    }
}

__global__ __launch_bounds__(256, 2)
void painn_edge_kernel(const float* __restrict__ s,
                       const float* __restrict__ v,
                       const float* __restrict__ rbf,
                       const float* __restrict__ evu,
                       const float* __restrict__ mW1,
                       const float* __restrict__ mb1,
                       const float* __restrict__ mW2,
                       const float* __restrict__ mb2,
                       const int*   __restrict__ eidx,
                       const int*   __restrict__ sorted,
                       int E,
                       float* __restrict__ agg_s,   // [N,H]   (d_out part 0)
                       float* __restrict__ agg_v)   // [N,3,H] (d_out part 1)
{
    __shared__ float Xs[BE * XS_STRIDE];   // x-tile for GEMM1, then reduce stage RS
    __shared__ float H1s[BE * H1_STRIDE];
    __shared__ float evus[BE][3];
    __shared__ int   eids[BE];
    __shared__ int   srcs[BE];
    __shared__ int   dsts[BE];

    const int t  = threadIdx.x;
    const int e0 = blockIdx.x * BE;

    if (t < BE) {
        const int e = sorted[e0 + t];
        eids[t] = e;
        srcs[t] = eidx[e];               // edge_index row 0
        dsts[t] = eidx[E + e];           // edge_index row 1 (sorted ascending-ish)
    }
    __syncthreads();

    if (t < BE * 3) {
        int r = t / 3, c = t - r * 3;
        evus[r][c] = evu[eids[r] * 3 + c];
    }

    // ---- gather x = [s[src], rbf] into Xs ----
    #pragma unroll
    for (int it = 0; it < 8; ++it) {
        int idx = t + it * 256;          // 0..2047 -> 64 rows x 32 float4
        int row = idx >> 5;
        int c4  = (idx & 31) << 2;
        const float4 val = *reinterpret_cast<const float4*>(s + srcs[row] * H + c4);
        float* p = &Xs[row * XS_STRIDE + c4];
        p[0] = val.x; p[1] = val.y; p[2] = val.z; p[3] = val.w;
    }
    #pragma unroll
    for (int it = 0; it < 5; ++it) {
        int idx = t + it * 256;          // 0..1279 -> 64 rows x 20
        int row = idx / R;
        int c   = idx - row * R;
        Xs[row * XS_STRIDE + H + c] = rbf[eids[row] * R + c];
    }
    __syncthreads();

    const int ty = t >> 4;               // 0..15
    const int tx = t & 15;               // 0..15
    const int jb = tx << 3;              // output col base (8 cols/thread)
    const int er = ty << 2;              // edge row base (4 edges/thread)

    // reducer mapping: each thread owns one column over a 32-row half
    const int rcol = t & 127;
    const int rr0  = (t >> 7) * 32;

    // ---- GEMM1: h1 = silu(x @ mW1 + mb1) ----
    {
        float acc[4][8];
        #pragma unroll
        for (int r2 = 0; r2 < 4; ++r2)
            #pragma unroll
            for (int j = 0; j < 8; ++j) acc[r2][j] = 0.f;

        const float* wp = mW1 + jb;
        for (int k = 0; k < KX; ++k) {
            const float4 w0 = *reinterpret_cast<const float4*>(wp);
            const float4 w1 = *reinterpret_cast<const float4*>(wp + 4);
            wp += H;
            float xk[4];
            #pragma unroll
            for (int r2 = 0; r2 < 4; ++r2) xk[r2] = Xs[(er + r2) * XS_STRIDE + k];
            #pragma unroll
            for (int r2 = 0; r2 < 4; ++r2) {
                acc[r2][0] += xk[r2] * w0.x;
                acc[r2][1] += xk[r2] * w0.y;
                acc[r2][2] += xk[r2] * w0.z;
                acc[r2][3] += xk[r2] * w0.w;
                acc[r2][4] += xk[r2] * w1.x;
                acc[r2][5] += xk[r2] * w1.y;
                acc[r2][6] += xk[r2] * w1.z;
                acc[r2][7] += xk[r2] * w1.w;
            }
        }
        const float4 b0 = *reinterpret_cast<const float4*>(mb1 + jb);
        const float4 b1 = *reinterpret_cast<const float4*>(mb1 + jb + 4);
        const float bias[8] = {b0.x, b0.y, b0.z, b0.w, b1.x, b1.y, b1.z, b1.w};
        #pragma unroll
        for (int r2 = 0; r2 < 4; ++r2) {
            #pragma unroll
            for (int j = 0; j < 8; ++j) {
                float a = acc[r2][j] + bias[j];
                H1s[(er + r2) * H1_STRIDE + jb + j] = silu_f(a);
            }
        }
    }
    __syncthreads();   // H1s ready; Xs reads done -> Xs reusable as RS stage

    // ---- GEMM2 chunk 0: a_ss -> LDS -> segmented reduce -> agg_s ----
    {
        float acc[4][8];
        #pragma unroll
        for (int r2 = 0; r2 < 4; ++r2)
            #pragma unroll
            for (int j = 0; j < 8; ++j) acc[r2][j] = 0.f;

        const float* wp = mW2 + jb;
        for (int k = 0; k < H; ++k) {
            const float4 w0 = *reinterpret_cast<const float4*>(wp);
            const float4 w1 = *reinterpret_cast<const float4*>(wp + 4);
            wp += 3 * H;
            float hk[4];
            #pragma unroll
            for (int r2 = 0; r2 < 4; ++r2) hk[r2] = H1s[(er + r2) * H1_STRIDE + k];
            #pragma unroll
            for (int r2 = 0; r2 < 4; ++r2) {
                acc[r2][0] += hk[r2] * w0.x;
                acc[r2][1] += hk[r2] * w0.y;
                acc[r2][2] += hk[r2] * w0.z;
                acc[r2][3] += hk[r2] * w0.w;
                acc[r2][4] += hk[r2] * w1.x;
                acc[r2][5] += hk[r2] * w1.y;
                acc[r2][6] += hk[r2] * w1.z;
                acc[r2][7] += hk[r2] * w1.w;
            }
        }
        const float4 b0 = *reinterpret_cast<const float4*>(mb2 + jb);
        const float4 b1 = *reinterpret_cast<const float4*>(mb2 + jb + 4);
        const float bias[8] = {b0.x, b0.y, b0.z, b0.w, b1.x, b1.y, b1.z, b1.w};
        #pragma unroll
        for (int r2 = 0; r2 < 4; ++r2)
            #pragma unroll
            for (int j = 0; j < 8; ++j)
                Xs[(er + r2) * XS_STRIDE + jb + j] = acc[r2][j] + bias[j];
        __syncthreads();

        // segmented run-sum over 32 rows per thread; flush on dst change
        float run = 0.f;
        int prev = dsts[rr0];
        for (int r = rr0; r < rr0 + 32; ++r) {
            const int d = dsts[r];
            if (d != prev) {
                unsafeAtomicAdd(&agg_s[prev * H + rcol], run);
                run = 0.f; prev = d;
            }
            run += Xs[r * XS_STRIDE + rcol];
        }
        unsafeAtomicAdd(&agg_s[prev * H + rcol], run);
    }
    __syncthreads();

    // ---- GEMM2 chunks 1&2: a_sv, a_vv; per-d combine -> LDS -> reduce -> agg_v ----
    {
        float asv[4][8], avv[4][8];
        #pragma unroll
        for (int r2 = 0; r2 < 4; ++r2)
            #pragma unroll
            for (int j = 0; j < 8; ++j) { asv[r2][j] = 0.f; avv[r2][j] = 0.f; }

        const float* wp = mW2 + H + jb;       // cols [128..256) and [256..384)
        for (int k = 0; k < H; ++k) {
            const float4 s0 = *reinterpret_cast<const float4*>(wp);
            const float4 s1 = *reinterpret_cast<const float4*>(wp + 4);
            const float4 v0 = *reinterpret_cast<const float4*>(wp + H);
            const float4 v1 = *reinterpret_cast<const float4*>(wp + H + 4);
            wp += 3 * H;
            float hk[4];
            #pragma unroll
            for (int r2 = 0; r2 < 4; ++r2) hk[r2] = H1s[(er + r2) * H1_STRIDE + k];
            #pragma unroll
            for (int r2 = 0; r2 < 4; ++r2) {
                asv[r2][0] += hk[r2] * s0.x;  avv[r2][0] += hk[r2] * v0.x;
                asv[r2][1] += hk[r2] * s0.y;  avv[r2][1] += hk[r2] * v0.y;
                asv[r2][2] += hk[r2] * s0.z;  avv[r2][2] += hk[r2] * v0.z;
                asv[r2][3] += hk[r2] * s0.w;  avv[r2][3] += hk[r2] * v0.w;
                asv[r2][4] += hk[r2] * s1.x;  avv[r2][4] += hk[r2] * v1.x;
                asv[r2][5] += hk[r2] * s1.y;  avv[r2][5] += hk[r2] * v1.y;
                asv[r2][6] += hk[r2] * s1.z;  avv[r2][6] += hk[r2] * v1.z;
                asv[r2][7] += hk[r2] * s1.w;  avv[r2][7] += hk[r2] * v1.w;
            }
        }
        const float4 bs0 = *reinterpret_cast<const float4*>(mb2 + H + jb);
        const float4 bs1 = *reinterpret_cast<const float4*>(mb2 + H + jb + 4);
        const float4 bv0 = *reinterpret_cast<const float4*>(mb2 + 2 * H + jb);
        const float4 bv1 = *reinterpret_cast<const float4*>(mb2 + 2 * H + jb + 4);
        float msv[4][8], mvv[4][8];
        #pragma unroll
        for (int r2 = 0; r2 < 4; ++r2) {
            msv[r2][0] = asv[r2][0] + bs0.x;  mvv[r2][0] = avv[r2][0] + bv0.x;
            msv[r2][1] = asv[r2][1] + bs0.y;  mvv[r2][1] = avv[r2][1] + bv0.y;
            msv[r2][2] = asv[r2][2] + bs0.z;  mvv[r2][2] = avv[r2][2] + bv0.z;
            msv[r2][3] = asv[r2][3] + bs0.w;  mvv[r2][3] = avv[r2][3] + bv0.w;
            msv[r2][4] = asv[r2][4] + bs1.x;  mvv[r2][4] = avv[r2][4] + bv1.x;
            msv[r2][5] = asv[r2][5] + bs1.y;  mvv[r2][5] = avv[r2][5] + bv1.y;
            msv[r2][6] = asv[r2][6] + bs1.z;  mvv[r2][6] = avv[r2][6] + bv1.z;
            msv[r2][7] = asv[r2][7] + bs1.w;  mvv[r2][7] = avv[r2][7] + bv1.w;
        }

        #pragma unroll
        for (int d = 0; d < 3; ++d) {
            // owners: msg = a_sv*evu_d + a_vv*v[src][d]  -> stage in Xs
            #pragma unroll
            for (int r2 = 0; r2 < 4; ++r2) {
                const int e  = er + r2;
                const int sn = srcs[e];
                const float ed = evus[e][d];
                const float* vp = v + (sn * 3 + d) * H + jb;
                const float4 vv0 = *reinterpret_cast<const float4*>(vp);
                const float4 vv1 = *reinterpret_cast<const float4*>(vp + 4);
                float* rp = &Xs[e * XS_STRIDE + jb];
                rp[0] = msv[r2][0] * ed + mvv[r2][0] * vv0.x;
                rp[1] = msv[r2][1] * ed + mvv[r2][1] * vv0.y;
                rp[2] = msv[r2][2] * ed + mvv[r2][2] * vv0.z;
                rp[3] = msv[r2][3] * ed + mvv[r2][3] * vv0.w;
                rp[4] = msv[r2][4] * ed + mvv[r2][4] * vv1.x;
                rp[5] = msv[r2][5] * ed + mvv[r2][5] * vv1.y;
                rp[6] = msv[r2][6] * ed + mvv[r2][6] * vv1.z;
                rp[7] = msv[r2][7] * ed + mvv[r2][7] * vv1.w;
            }
            __syncthreads();

            // reducers: segmented run-sum into agg_v[(dst*3+d)*H + col]
            float run = 0.f;
            int prev = dsts[rr0];
            for (int r = rr0; r < rr0 + 32; ++r) {
                const int dn = dsts[r];
                if (dn != prev) {
                    unsafeAtomicAdd(&agg_v[(prev * 3 + d) * H + rcol], run);
                    run = 0.f; prev = dn;
                }
                run += Xs[r * XS_STRIDE + rcol];
            }
            unsafeAtomicAdd(&agg_v[(prev * 3 + d) * H + rcol], run);
            __syncthreads();
        }
    }
}

__global__ __launch_bounds__(256, 1)
void painn_node_kernel(const float* __restrict__ s,
                       const float* __restrict__ v,
                       const float* __restrict__ uW1,
                       const float* __restrict__ ub1,
                       const float* __restrict__ uW2,
                       const float* __restrict__ ub2,
                       const float* __restrict__ ln_g,
                       const float* __restrict__ ln_b,
                       int N,
                       float* __restrict__ out_s,   // in: agg_s, out: s_out
                       float* __restrict__ out_v)   // in: agg_v, out: v_out
{
    __shared__ float Us[BN * US_STRIDE];   // [64][256+pad] : [s+agg_s | v_norm], later y
    __shared__ float H2s[BN * H2_STRIDE];

    const int t  = threadIdx.x;
    const int n0 = blockIdx.x * BN;
    const int m  = min(BN, N - n0);

    // ---- load s+agg_s and compute v_norm into Us ----
    #pragma unroll
    for (int it = 0; it < 8; ++it) {
        int idx = t + it * 256;
        int row = idx >> 5;
        int c4  = (idx & 31) << 2;
        if (row < m) {
            const int nb = (n0 + row) * H + c4;
            const float4 sv = *reinterpret_cast<const float4*>(s + nb);
            const float4 av = *reinterpret_cast<const float4*>(out_s + nb);
            float* p = &Us[row * US_STRIDE + c4];
            p[0] = sv.x + av.x; p[1] = sv.y + av.y;
            p[2] = sv.z + av.z; p[3] = sv.w + av.w;

            float nx = 0.f, ny = 0.f, nz = 0.f, nw = 0.f;
            #pragma unroll
            for (int d = 0; d < 3; ++d) {
                const int vb = ((n0 + row) * 3 + d) * H + c4;
                const float4 vv = *reinterpret_cast<const float4*>(v + vb);
                const float4 avv = *reinterpret_cast<const float4*>(out_v + vb);
                const float a0 = vv.x + avv.x, a1 = vv.y + avv.y;
                const float a2 = vv.z + avv.z, a3 = vv.w + avv.w;
                nx += a0 * a0; ny += a1 * a1; nz += a2 * a2; nw += a3 * a3;
            }
            float* q = &Us[row * US_STRIDE + H + c4];
            q[0] = sqrtf(nx); q[1] = sqrtf(ny); q[2] = sqrtf(nz); q[3] = sqrtf(nw);
        }
    }
    __syncthreads();

    const int ty = t >> 4;
    const int tx = t & 15;
    const int jb = tx << 3;
    const int nr = ty << 2;

    // ---- GEMV1: silu(upd_in @ uW1 + ub1) -> H2s ----
    {
        float acc[4][8];
        #pragma unroll
        for (int r2 = 0; r2 < 4; ++r2)
            #pragma unroll
            for (int j = 0; j < 8; ++j) acc[r2][j] = 0.f;

        const float* wp = uW1 + jb;
        for (int k = 0; k < 2 * H; ++k) {
            const float4 w0 = *reinterpret_cast<const float4*>(wp);
            const float4 w1 = *reinterpret_cast<const float4*>(wp + 4);
            wp += H;
            float uk[4];
            #pragma unroll
            for (int r2 = 0; r2 < 4; ++r2) uk[r2] = Us[(nr + r2) * US_STRIDE + k];
            #pragma unroll
            for (int r2 = 0; r2 < 4; ++r2) {
                acc[r2][0] += uk[r2] * w0.x;
                acc[r2][1] += uk[r2] * w0.y;
                acc[r2][2] += uk[r2] * w0.z;
                acc[r2][3] += uk[r2] * w0.w;
                acc[r2][4] += uk[r2] * w1.x;
                acc[r2][5] += uk[r2] * w1.y;
                acc[r2][6] += uk[r2] * w1.z;
                acc[r2][7] += uk[r2] * w1.w;
            }
        }
        const float4 b0 = *reinterpret_cast<const float4*>(ub1 + jb);
        const float4 b1 = *reinterpret_cast<const float4*>(ub1 + jb + 4);
        const float bias[8] = {b0.x, b0.y, b0.z, b0.w, b1.x, b1.y, b1.z, b1.w};
        #pragma unroll
        for (int r2 = 0; r2 < 4; ++r2)
            #pragma unroll
            for (int j = 0; j < 8; ++j)
                H2s[(nr + r2) * H2_STRIDE + jb + j] = silu_f(acc[r2][j] + bias[j]);
    }
    __syncthreads();

    // ---- GEMV2: delta_s & gate; y = s + delta_s into Us ----
    float gate[4][8];
    {
        float ad[4][8], ag[4][8];
        #pragma unroll
        for (int r2 = 0; r2 < 4; ++r2)
            #pragma unroll
            for (int j = 0; j < 8; ++j) { ad[r2][j] = 0.f; ag[r2][j] = 0.f; }

        const float* wp = uW2 + jb;
        for (int k = 0; k < H; ++k) {
            const float4 d0 = *reinterpret_cast<const float4*>(wp);
            const float4 d1 = *reinterpret_cast<const float4*>(wp + 4);
            const float4 g0 = *reinterpret_cast<const float4*>(wp + H);
            const float4 g1 = *reinterpret_cast<const float4*>(wp + H + 4);
            wp += 2 * H;
            float hk[4];
            #pragma unroll
            for (int r2 = 0; r2 < 4; ++r2) hk[r2] = H2s[(nr + r2) * H2_STRIDE + k];
            #pragma unroll
            for (int r2 = 0; r2 < 4; ++r2) {
                ad[r2][0] += hk[r2] * d0.x;  ag[r2][0] += hk[r2] * g0.x;
                ad[r2][1] += hk[r2] * d0.y;  ag[r2][1] += hk[r2] * g0.y;
                ad[r2][2] += hk[r2] * d0.z;  ag[r2][2] += hk[r2] * g0.z;
                ad[r2][3] += hk[r2] * d0.w;  ag[r2][3] += hk[r2] * g0.w;
                ad[r2][4] += hk[r2] * d1.x;  ag[r2][4] += hk[r2] * g1.x;
                ad[r2][5] += hk[r2] * d1.y;  ag[r2][5] += hk[r2] * g1.y;
                ad[r2][6] += hk[r2] * d1.z;  ag[r2][6] += hk[r2] * g1.z;
                ad[r2][7] += hk[r2] * d1.w;  ag[r2][7] += hk[r2] * g1.w;
            }
        }
        const float4 bd0 = *reinterpret_cast<const float4*>(ub2 + jb);
        const float4 bd1 = *reinterpret_cast<const float4*>(ub2 + jb + 4);
        const float4 bg0 = *reinterpret_cast<const float4*>(ub2 + H + jb);
        const float4 bg1 = *reinterpret_cast<const float4*>(ub2 + H + jb + 4);
        const float bd[8] = {bd0.x, bd0.y, bd0.z, bd0.w, bd1.x, bd1.y, bd1.z, bd1.w};
        const float bg[8] = {bg0.x, bg0.y, bg0.z, bg0.w, bg1.x, bg1.y, bg1.z, bg1.w};

        #pragma unroll
        for (int r2 = 0; r2 < 4; ++r2) {
            #pragma unroll
            for (int j = 0; j < 8; ++j) gate[r2][j] = ag[r2][j] + bg[j];
            if (nr + r2 < m) {
                const int nb = (n0 + nr + r2) * H + jb;
                const float4 s0 = *reinterpret_cast<const float4*>(s + nb);
                const float4 s1 = *reinterpret_cast<const float4*>(s + nb + 4);
                const float sl[8] = {s0.x, s0.y, s0.z, s0.w, s1.x, s1.y, s1.z, s1.w};
                float* yp = &Us[(nr + r2) * US_STRIDE + jb];
                #pragma unroll
                for (int j = 0; j < 8; ++j) yp[j] = sl[j] + ad[r2][j] + bd[j];
            }
        }
    }
    __syncthreads();

    // ---- LayerNorm on y (4 threads per row) -> s_out ----
    {
        const int row = t >> 2;
        const int q   = t & 3;
        if (row < m) {
            float sum = 0.f, ss = 0.f;
            #pragma unroll
            for (int i = 0; i < 32; ++i) {
                const float val = Us[row * US_STRIDE + q * 32 + i];
                sum += val; ss += val * val;
            }
            sum += __shfl_xor(sum, 1); ss += __shfl_xor(ss, 1);
            sum += __shfl_xor(sum, 2); ss += __shfl_xor(ss, 2);
            const float mu   = sum * (1.0f / H);
            const float var  = ss * (1.0f / H) - mu * mu;
            const float rstd = rsqrtf(fmaxf(var, 0.f) + LN_EPS);
            #pragma unroll
            for (int i4 = 0; i4 < 8; ++i4) {
                const int c = q * 32 + i4 * 4;
                const float4 g = *reinterpret_cast<const float4*>(ln_g + c);
                const float4 b = *reinterpret_cast<const float4*>(ln_b + c);
                const float* yp = &Us[row * US_STRIDE + c];
                float4 o;
                o.x = (yp[0] - mu) * rstd * g.x + b.x;
                o.y = (yp[1] - mu) * rstd * g.y + b.y;
                o.z = (yp[2] - mu) * rstd * g.z + b.z;
                o.w = (yp[3] - mu) * rstd * g.w + b.w;
                *reinterpret_cast<float4*>(out_s + (n0 + row) * H + c) = o;
            }
        }
    }

    // ---- v_out = gate * (v + agg_v), in place over agg_v ----
    #pragma unroll
    for (int r2 = 0; r2 < 4; ++r2) {
        if (nr + r2 < m) {
            const int nn = n0 + nr + r2;
            #pragma unroll
            for (int d = 0; d < 3; ++d) {
                const int vb = (nn * 3 + d) * H + jb;
                const float4 vv0 = *reinterpret_cast<const float4*>(v + vb);
                const float4 vv1 = *reinterpret_cast<const float4*>(v + vb + 4);
                const float4 av0 = *reinterpret_cast<const float4*>(out_v + vb);
                const float4 av1 = *reinterpret_cast<const float4*>(out_v + vb + 4);
                float4 o0, o1;
                o0.x = gate[r2][0] * (vv0.x + av0.x);
                o0.y = gate[r2][1] * (vv0.y + av0.y);
                o0.z = gate[r2][2] * (vv0.z + av0.z);
                o0.w = gate[r2][3] * (vv0.w + av0.w);
                o1.x = gate[r2][4] * (vv1.x + av1.x);
                o1.y = gate[r2][5] * (vv1.y + av1.y);
                o1.z = gate[r2][6] * (vv1.z + av1.z);
                o1.w = gate[r2][7] * (vv1.w + av1.w);
                *reinterpret_cast<float4*>(out_v + vb)     = o0;
                *reinterpret_cast<float4*>(out_v + vb + 4) = o1;
            }
        }
    }
}

extern "C" void kernel_launch(void* const* d_in, const int* in_sizes, int n_in,
                              void* d_out, int out_size, void* d_ws, size_t ws_size,
                              hipStream_t stream)
{
    const float* s    = (const float*)d_in[0];
    const float* v    = (const float*)d_in[1];
    const float* rbf  = (const float*)d_in[2];
    const float* evu  = (const float*)d_in[3];
    const float* mW1  = (const float*)d_in[4];
    const float* mb1  = (const float*)d_in[5];
    const float* mW2  = (const float*)d_in[6];
    const float* mb2  = (const float*)d_in[7];
    const float* uW1  = (const float*)d_in[8];
    const float* ub1  = (const float*)d_in[9];
    const float* uW2  = (const float*)d_in[10];
    const float* ub2  = (const float*)d_in[11];
    const float* ln_g = (const float*)d_in[12];
    const float* ln_b = (const float*)d_in[13];
    const int*   eidx = (const int*)d_in[14];

    const int N = in_sizes[0] / H;   // 50000
    const int E = in_sizes[2] / R;   // 800000

    float* agg_s = (float*)d_out;                 // [N,H]
    float* agg_v = (float*)d_out + (size_t)N * H; // [N,3,H]

    // workspace layout: cnt[N] | fill[N] | sorted[E]  (~3.6 MB)
    int* cnt    = (int*)d_ws;
    int* fill   = cnt + N;
    int* sorted = fill + N;

    // zero agg buffers (d_out re-poisoned to 0xAA before every call) + counters
    const long n4 = (long)N * 4 * H / 4;          // float4 count
    zero_f4_kernel<<<dim3(2048), dim3(256), 0, stream>>>((float4*)d_out, n4);
    zero_i_kernel<<<dim3(64), dim3(256), 0, stream>>>(cnt, N);

    // counting sort of edges by destination
    hist_kernel<<<dim3(2048), dim3(256), 0, stream>>>(eidx, E, cnt);
    scan_kernel<<<dim3(1), dim3(1024), 0, stream>>>(cnt, N, fill);
    scatter_kernel<<<dim3(2048), dim3(256), 0, stream>>>(eidx, E, fill, sorted);

    painn_edge_kernel<<<dim3(E / BE), dim3(256), 0, stream>>>(
        s, v, rbf, evu, mW1, mb1, mW2, mb2, eidx, sorted, E, agg_s, agg_v);

    painn_node_kernel<<<dim3((N + BN - 1) / BN), dim3(256), 0, stream>>>(
        s, v, uW1, ub1, uW2, ub2, ln_g, ln_b, N, agg_s, agg_v);
}